// Round 9
// baseline (977.837 us; speedup 1.0000x reference)
//
#include <hip/hip_runtime.h>
#include <hip/hip_bf16.h>
#include <stdint.h>

#define BATCH 8192
#define DDIM 1024
#define EPSN 1e-8f

typedef __bf16 bf16x8 __attribute__((ext_vector_type(8)));
typedef float f32x4 __attribute__((ext_vector_type(4)));

// ws layout (floats):
//   +0     : part_pc[2048]  (prep: pre-scaled center+ce partials)
//   +2080  : part_soft[528]
//   +8192  : fn bf16 [8192][1024]  (16 MiB)
#define WS_PC   0
#define WS_SOFT 2080
#define WS_FN   8192

__device__ __forceinline__ unsigned short f2bf(float x) {
    unsigned int u = __builtin_bit_cast(unsigned int, x);
    unsigned int r = (u + 0x7fffu + ((u >> 16) & 1u)) >> 16;
    return (unsigned short)r;
}

__device__ __forceinline__ void gload16(const void* g, void* l) {
    __builtin_amdgcn_global_load_lds(
        (const __attribute__((address_space(1))) void*)g,
        (__attribute__((address_space(3))) void*)l, 16, 0, 0);
}

// ---------------- prep: row norms -> fn (bf16), center loss + CE partials ----
__global__ __launch_bounds__(256) void prep_kernel(
    const float* __restrict__ feat, const int* __restrict__ labels,
    const float* __restrict__ logits, const float* __restrict__ centers,
    float* __restrict__ part_pc, unsigned short* __restrict__ fn)
{
    __shared__ float pr[4];
    int wave = threadIdx.x >> 6;
    int lane = threadIdx.x & 63;
    int row  = blockIdx.x * 4 + wave;
    const float* frow = feat + (size_t)row * DDIM;
    int lab = labels[row];
    const float* crow = centers + (size_t)lab * DDIM;

    float4 f[4];
    float ss = 0.f, cp = 0.f;
#pragma unroll
    for (int q = 0; q < 4; q++) {
        f[q] = *(const float4*)(frow + q * 256 + lane * 4);
        float4 cv = *(const float4*)(crow + q * 256 + lane * 4);
        ss += f[q].x * f[q].x + f[q].y * f[q].y + f[q].z * f[q].z + f[q].w * f[q].w;
        float dx = f[q].x - cv.x, dy = f[q].y - cv.y, dz = f[q].z - cv.z, dw = f[q].w - cv.w;
        cp += dx * dx + dy * dy + dz * dz + dw * dw;
    }
#pragma unroll
    for (int o = 32; o > 0; o >>= 1) {
        ss += __shfl_xor(ss, o);
        cp += __shfl_xor(cp, o);
    }
    float scale = 1.0f / fmaxf(sqrtf(ss), EPSN);
#pragma unroll
    for (int q = 0; q < 4; q++) {
        ushort4 o4;
        o4.x = f2bf(f[q].x * scale);
        o4.y = f2bf(f[q].y * scale);
        o4.z = f2bf(f[q].z * scale);
        o4.w = f2bf(f[q].w * scale);
        *(ushort4*)(fn + (size_t)row * DDIM + q * 256 + lane * 4) = o4;
    }
    if (lane == 0) {
        // fused CE for this row (8 logits, one lane)
        const float* lg = logits + (size_t)row * 8;
        float4 a = *(const float4*)lg;
        float4 b = *(const float4*)(lg + 4);
        float lv[8] = {a.x, a.y, a.z, a.w, b.x, b.y, b.z, b.w};
        float m = lv[0];
#pragma unroll
        for (int k = 1; k < 8; k++) m = fmaxf(m, lv[k]);
        float s = 0.f;
#pragma unroll
        for (int k = 0; k < 8; k++) s += __expf(lv[k] - m);
        float ce = (m + __logf(s)) - lv[lab];
        pr[wave] = cp * (0.5f / (float)BATCH) + ce * (1.0f / (float)BATCH);
    }
    __syncthreads();
    if (threadIdx.x == 0) part_pc[blockIdx.x] = pr[0] + pr[1] + pr[2] + pr[3];
}

// ---------------- soft-cosine: 256^2 tile, 4-slot ring, 2 blocks/CU ----------
// Regions s = 4t+r, r = 0:A0 1:B0 2:A1 3:B1, each [256][32] bf16 (16KB, 2 loads/thread).
// Slot = s&3 (64 KB total). Issue-after-last-read schedule (one region per phase):
//   P0(4t): s=4t+6   P1: s=4t+5   P2: s=4t+4   P3: s=4t+7
// Slot-overwrite lands >= 1 barrier after the slot's last reader (derived r9).
// FIFO-exact waits: P1 vmcnt(4) -> s<=4t+3 landed (covers P2 reads);
//                   P3 vmcnt(2) -> s<=4t+5 landed (covers next P0 reads; FIFO
//                   retire-through also lands 4t+6, issued earlier).
// Tail t=15: no issues; P1 vmcnt(0) covers s=62,63; P3 no wait.
// M-split phases: P0/P2 read a[0..3]+b[0..3] (8 ds_read_b128, 16 MFMA);
// P1/P3 read a[4..7] (4 reads, 16 MFMA, b reused in regs).
// LDS XOR-swizzle chunk16 ^ ((row>>1)&3) on staging source and ds_read.

__global__ __launch_bounds__(512, 4) void soft_kernel(
    const unsigned short* __restrict__ fn, const int* __restrict__ labels,
    const float* __restrict__ sim, float* __restrict__ part_soft)
{
    __shared__ __align__(16) unsigned short tiles[4][256][32];  // 64 KiB
    __shared__ int lrow[256], lcol[256];
    __shared__ float Ssm[64], W2s[64];
    __shared__ float red[8];

    int tid  = threadIdx.x;
    int lane = tid & 63;
    int w    = tid >> 6;
    int wr   = w >> 2, wc = w & 3;      // 2x4 wave grid; wave owns 128x64
    int lr16 = lane & 15;
    int kgrp = lane >> 4;

    // triangle decode with bijective XCD swizzle (528 = 8*66)
    int b0i = blockIdx.x;
    int swz = (b0i & 7) * 66 + (b0i >> 3);
    int tr = 0, rem = swz;
    while (rem >= 32 - tr) { rem -= 32 - tr; tr++; }
    int tc = tr + rem;
    bool diag = (tr == tc);

    const unsigned short* Abase = fn + (size_t)tr * 256 * DDIM;
    const unsigned short* Bbase = fn + (size_t)tc * 256 * DDIM;

    // staging geometry: region = 1024 slots of 16B; thread covers idx = {tid, 512+tid}
    int myrow  = tid >> 2;                     // 0..127 (second load adds 128)
    int mychk  = tid & 3;
    int mycol8 = mychk ^ ((myrow >> 1) & 3);   // pre-swizzled global source
    int goff0  = myrow * DDIM + mycol8 * 8;

    auto ISSUE = [&](int s) {
        int kt_s = s >> 2, r = s & 3, kk = r >> 1;
        const unsigned short* gb = (r & 1) ? Bbase : Abase;
        const unsigned short* g0 = gb + goff0 + kt_s * 64 + kk * 32;
        unsigned short* l0 = &tiles[s & 3][0][0] + tid * 8;
        gload16(g0, l0);
        gload16(g0 + 128 * DDIM, l0 + 512 * 8);
    };

    // prologue: stage regions 0..3 (8 loads); wait regions {0,1} (outstanding {2,3}=4)
#pragma unroll
    for (int s = 0; s < 4; s++) ISSUE(s);
    if (tid < 256) {
        lrow[tid] = labels[tr * 256 + tid];
        lcol[tid] = labels[tc * 256 + tid];
    }
    if (tid < 64) {
        float sv = sim[tid];
        Ssm[tid] = sv;
        W2s[tid] = sv + sim[(tid & 7) * 8 + (tid >> 3)];
    }
    asm volatile("s_waitcnt vmcnt(4) lgkmcnt(0)" ::: "memory");
    __builtin_amdgcn_s_barrier();
    asm volatile("" ::: "memory");

    f32x4 acc[8][4] = {};
    bf16x8 av[4], bv[4];

#define VMW(N) asm volatile("s_waitcnt vmcnt(" #N ")" ::: "memory");
#define NOVM

#define PH0(KK, DOISS, S, WAIT) { \
    if (DOISS) ISSUE(S); \
    const unsigned short* Ar = &tiles[(KK)*2][0][0]; \
    const unsigned short* Br = &tiles[(KK)*2+1][0][0]; \
    _Pragma("unroll") \
    for (int j = 0; j < 4; j++) { \
        int row = wr * 128 + j * 16 + lr16; \
        av[j] = *(const bf16x8*)((const char*)Ar + row * 64 + ((kgrp ^ ((row >> 1) & 3)) * 16)); \
        int col = wc * 64 + j * 16 + lr16; \
        bv[j] = *(const bf16x8*)((const char*)Br + col * 64 + ((kgrp ^ ((col >> 1) & 3)) * 16)); \
    } \
    WAIT \
    __builtin_amdgcn_s_barrier(); \
    asm volatile("" ::: "memory"); \
    __builtin_amdgcn_s_setprio(1); \
    _Pragma("unroll") \
    for (int j = 0; j < 4; j++) \
        _Pragma("unroll") \
        for (int n = 0; n < 4; n++) \
            acc[j][n] = __builtin_amdgcn_mfma_f32_16x16x32_bf16(av[j], bv[n], acc[j][n], 0, 0, 0); \
    __builtin_amdgcn_s_setprio(0); \
}

#define PH1(KK, DOISS, S, WAIT) { \
    if (DOISS) ISSUE(S); \
    const unsigned short* Ar = &tiles[(KK)*2][0][0]; \
    _Pragma("unroll") \
    for (int j = 0; j < 4; j++) { \
        int row = wr * 128 + 64 + j * 16 + lr16; \
        av[j] = *(const bf16x8*)((const char*)Ar + row * 64 + ((kgrp ^ ((row >> 1) & 3)) * 16)); \
    } \
    WAIT \
    __builtin_amdgcn_s_barrier(); \
    asm volatile("" ::: "memory"); \
    __builtin_amdgcn_s_setprio(1); \
    _Pragma("unroll") \
    for (int j = 0; j < 4; j++) \
        _Pragma("unroll") \
        for (int n = 0; n < 4; n++) \
            acc[4 + j][n] = __builtin_amdgcn_mfma_f32_16x16x32_bf16(av[j], bv[n], acc[4 + j][n], 0, 0, 0); \
    __builtin_amdgcn_s_setprio(0); \
}

    // main loop: t = 0..14, all issues valid (max s = 4*14+7 = 63)
    for (int t = 0; t < 15; t++) {
        int qb = t * 4;
        PH0(0, 1, qb + 6, NOVM)
        PH1(0, 1, qb + 5, VMW(4))
        PH0(1, 1, qb + 4, NOVM)
        PH1(1, 1, qb + 7, VMW(2))
    }
    // tail t = 15: no issues
    PH0(0, 0, 0, NOVM)
    PH1(0, 0, 0, VMW(0))
    PH0(1, 0, 0, NOVM)
    PH1(1, 0, 0, NOVM)

#undef PH0
#undef PH1
#undef VMW
#undef NOVM

    // epilogue: sum w_ij * relu(1 - cos) over this 256x256 tile
    float local = 0.f;
    int lb[4], cc[4];
#pragma unroll
    for (int n = 0; n < 4; n++) { cc[n] = wc * 64 + n * 16 + lr16; lb[n] = lcol[cc[n]]; }
#pragma unroll
    for (int m = 0; m < 8; m++) {
#pragma unroll
        for (int rg = 0; rg < 4; rg++) {
            int r = wr * 128 + m * 16 + kgrp * 4 + rg;
            int la8 = lrow[r] * 8;
#pragma unroll
            for (int n = 0; n < 4; n++) {
                float v = fmaxf(1.0f - acc[m][n][rg], 0.f);
                float wgt = diag ? ((r == cc[n]) ? 0.f : Ssm[la8 + lb[n]])
                                 : W2s[la8 + lb[n]];
                local += wgt * v;
            }
        }
    }
#pragma unroll
    for (int o = 32; o > 0; o >>= 1) local += __shfl_xor(local, o);
    if (lane == 0) red[w] = local;
    __syncthreads();
    if (tid == 0) {
        float s = 0.f;
#pragma unroll
        for (int k = 0; k < 8; k++) s += red[k];
        part_soft[blockIdx.x] = s;
    }
}

// ---------------- finalize: reduce all partials ----------------
__global__ __launch_bounds__(512) void finalize_kernel(
    const float* __restrict__ ws, float* __restrict__ out)
{
    __shared__ float red[8];
    int tid = threadIdx.x;
    const float invBB = 1.0f / ((float)BATCH * (float)(BATCH - 1));

    float local = 0.f;
    for (int i = tid; i < 2048; i += 512) local += ws[WS_PC + i];  // pre-scaled
    local += ws[WS_SOFT + tid] * invBB;                            // 0..511
    if (tid < 16) local += ws[WS_SOFT + 512 + tid] * invBB;        // 512..527

#pragma unroll
    for (int o = 32; o > 0; o >>= 1) local += __shfl_xor(local, o);
    if ((tid & 63) == 0) red[tid >> 6] = local;
    __syncthreads();
    if (tid == 0) {
        float s = 0.f;
#pragma unroll
        for (int k = 0; k < 8; k++) s += red[k];
        out[0] = s;
    }
}

extern "C" void kernel_launch(void* const* d_in, const int* in_sizes, int n_in,
                              void* d_out, int out_size, void* d_ws, size_t ws_size,
                              hipStream_t stream)
{
    const float* feat    = (const float*)d_in[0];
    const int*   labels  = (const int*)d_in[1];
    const float* logits  = (const float*)d_in[2];
    const float* sim     = (const float*)d_in[3];
    const float* centers = (const float*)d_in[4];
    float* out = (float*)d_out;

    float* ws = (float*)d_ws;
    unsigned short* fn = (unsigned short*)((char*)d_ws + WS_FN * 4);

    prep_kernel<<<BATCH / 4, 256, 0, stream>>>(feat, labels, logits, centers, ws + WS_PC, fn);
    soft_kernel<<<528, 512, 0, stream>>>(fn, labels, sim, ws + WS_SOFT);
    finalize_kernel<<<1, 512, 0, stream>>>(ws, out);
}

// Round 10
// 175.408 us; speedup vs baseline: 5.5747x; 5.5747x over previous
//
#include <hip/hip_runtime.h>
#include <hip/hip_bf16.h>
#include <stdint.h>

#define BATCH 8192
#define DDIM 1024
#define EPSN 1e-8f

typedef __bf16 bf16x8 __attribute__((ext_vector_type(8)));
typedef float f32x4 __attribute__((ext_vector_type(4)));

// ws layout (floats):
//   +0     : part_pc[2048]  (prep: pre-scaled center+ce partials)
//   +2080  : part_soft[1056]
//   +8192  : fn bf16 [8192][1024]  (16 MiB)
#define WS_PC   0
#define WS_SOFT 2080
#define WS_FN   8192

__device__ __forceinline__ unsigned short f2bf(float x) {
    unsigned int u = __builtin_bit_cast(unsigned int, x);
    unsigned int r = (u + 0x7fffu + ((u >> 16) & 1u)) >> 16;
    return (unsigned short)r;
}

__device__ __forceinline__ void gload16(const void* g, void* l) {
    __builtin_amdgcn_global_load_lds(
        (const __attribute__((address_space(1))) void*)g,
        (__attribute__((address_space(3))) void*)l, 16, 0, 0);
}

// ---------------- prep: row norms -> fn (bf16), center loss + CE partials ----
__global__ __launch_bounds__(256) void prep_kernel(
    const float* __restrict__ feat, const int* __restrict__ labels,
    const float* __restrict__ logits, const float* __restrict__ centers,
    float* __restrict__ part_pc, unsigned short* __restrict__ fn)
{
    __shared__ float pr[4];
    int wave = threadIdx.x >> 6;
    int lane = threadIdx.x & 63;
    int row  = blockIdx.x * 4 + wave;
    const float* frow = feat + (size_t)row * DDIM;
    int lab = labels[row];
    const float* crow = centers + (size_t)lab * DDIM;

    float4 f[4];
    float ss = 0.f, cp = 0.f;
#pragma unroll
    for (int q = 0; q < 4; q++) {
        f[q] = *(const float4*)(frow + q * 256 + lane * 4);
        float4 cv = *(const float4*)(crow + q * 256 + lane * 4);
        ss += f[q].x * f[q].x + f[q].y * f[q].y + f[q].z * f[q].z + f[q].w * f[q].w;
        float dx = f[q].x - cv.x, dy = f[q].y - cv.y, dz = f[q].z - cv.z, dw = f[q].w - cv.w;
        cp += dx * dx + dy * dy + dz * dz + dw * dw;
    }
#pragma unroll
    for (int o = 32; o > 0; o >>= 1) {
        ss += __shfl_xor(ss, o);
        cp += __shfl_xor(cp, o);
    }
    float scale = 1.0f / fmaxf(sqrtf(ss), EPSN);
#pragma unroll
    for (int q = 0; q < 4; q++) {
        ushort4 o4;
        o4.x = f2bf(f[q].x * scale);
        o4.y = f2bf(f[q].y * scale);
        o4.z = f2bf(f[q].z * scale);
        o4.w = f2bf(f[q].w * scale);
        *(ushort4*)(fn + (size_t)row * DDIM + q * 256 + lane * 4) = o4;
    }
    if (lane == 0) {
        const float* lg = logits + (size_t)row * 8;
        float4 a = *(const float4*)lg;
        float4 b = *(const float4*)(lg + 4);
        float lv[8] = {a.x, a.y, a.z, a.w, b.x, b.y, b.z, b.w};
        float m = lv[0];
#pragma unroll
        for (int k = 1; k < 8; k++) m = fmaxf(m, lv[k]);
        float s = 0.f;
#pragma unroll
        for (int k = 0; k < 8; k++) s += __expf(lv[k] - m);
        float ce = (m + __logf(s)) - lv[lab];
        pr[wave] = cp * (0.5f / (float)BATCH) + ce * (1.0f / (float)BATCH);
    }
    __syncthreads();
    if (threadIdx.x == 0) part_pc[blockIdx.x] = pr[0] + pr[1] + pr[2] + pr[3];
}

// ---------------- soft-cosine: 256x128 tile, 3-slot ring, 2 blocks/CU --------
// Region s (K-step, BK=32) = A[256][32] + B[128][32] bf16 = 24KB, 3 loads/thread.
// Ring slot = s%3 (72KB). Phase q: ISSUE(q+2) into slot (q+2)%3 (= region q-1's
// slot, freed at barrier q-1); 8 ds_read_b128 of region q; vmcnt(3) (-> region
// q+1 landed, covers phase q+1 reads); barrier; 16 MFMA.
// Tail: phase 30 vmcnt(0), phase 31 no wait. Prologue: ISSUE(0,1), vmcnt(3).
// Tiles: (tr,tc) with tc >= 2*tr (1056 total); per-element weight
// (gc > gr) ? S[la][lb]+S[lb][la] : 0 -- handles diagonal straddle uniformly.
// Wave grid 4x2, wave tile 64x64 -> acc[4][4] f32x4 = 64 VGPRs (fits 128 cap).
// LDS XOR-swizzle chunk16 ^ ((row>>1)&3), region-local row, both sides.

__global__ __launch_bounds__(512, 4) void soft_kernel(
    const unsigned short* __restrict__ fn, const int* __restrict__ labels,
    const float* __restrict__ sim, float* __restrict__ part_soft)
{
    __shared__ __align__(16) unsigned short tiles[3][384][32];  // 72 KiB
    __shared__ int lrow[256], lcol[128];
    __shared__ float Ssm[64], W2s[64];
    __shared__ float red[8];

    int tid  = threadIdx.x;
    int lane = tid & 63;
    int w    = tid >> 6;
    int wr   = w >> 1, wc = w & 1;      // 4x2 wave grid; wave owns 64x64
    int lr16 = lane & 15;
    int kgrp = lane >> 4;

    // tile decode with bijective XCD swizzle (1056 = 8*132)
    int b0i = blockIdx.x;
    int swz = (b0i & 7) * 132 + (b0i >> 3);
    int tr = 0, rem = swz;
    while (rem >= 64 - 2 * tr) { rem -= 64 - 2 * tr; tr++; }
    int tc = 2 * tr + rem;

    const unsigned short* Abase = fn + (size_t)tr * 256 * DDIM;
    const unsigned short* Bbase = fn + (size_t)tc * 128 * DDIM;

    // staging: A = 1024 chunks of 16B (thread: {tid, 512+tid}); B = 512 chunks ({tid})
    int myrow  = tid >> 2;                     // 0..127
    int mychk  = tid & 3;
    int mycol8 = mychk ^ ((myrow >> 1) & 3);   // pre-swizzled global source
    int goff0  = myrow * DDIM + mycol8 * 8;

    auto ISSUE = [&](int s) {
        unsigned short* Al = &tiles[s % 3][0][0];
        const unsigned short* gA = Abase + goff0 + s * 32;
        gload16(gA, Al + tid * 8);
        gload16(gA + 128 * DDIM, Al + (512 + tid) * 8);
        const unsigned short* gB = Bbase + goff0 + s * 32;
        gload16(gB, Al + 256 * 32 + tid * 8);
    };

    // prologue: regions 0,1; wait region 0 landed (outstanding {1} = 3)
    ISSUE(0);
    ISSUE(1);
    if (tid < 256) lrow[tid] = labels[tr * 256 + tid];
    if (tid >= 256 && tid < 384) lcol[tid - 256] = labels[tc * 128 + (tid - 256)];
    if (tid < 64) {
        float sv = sim[tid];
        Ssm[tid] = sv;
        W2s[tid] = sv + sim[(tid & 7) * 8 + (tid >> 3)];
    }
    asm volatile("s_waitcnt vmcnt(3) lgkmcnt(0)" ::: "memory");
    __builtin_amdgcn_s_barrier();
    asm volatile("" ::: "memory");

    f32x4 acc[4][4] = {};
    bf16x8 av[4], bv[4];

#define VMW(N) asm volatile("s_waitcnt vmcnt(" #N ")" ::: "memory");
#define NOVM

#define PHASE(SLOT, S, WAIT) { \
    if ((S) <= 31) ISSUE(S); \
    const unsigned short* Ar = &tiles[SLOT][0][0]; \
    const unsigned short* Br = &tiles[SLOT][256][0]; \
    _Pragma("unroll") \
    for (int j = 0; j < 4; j++) { \
        int row = wr * 64 + j * 16 + lr16; \
        av[j] = *(const bf16x8*)((const char*)Ar + row * 64 + ((kgrp ^ ((row >> 1) & 3)) * 16)); \
        int col = wc * 64 + j * 16 + lr16; \
        bv[j] = *(const bf16x8*)((const char*)Br + col * 64 + ((kgrp ^ ((col >> 1) & 3)) * 16)); \
    } \
    WAIT \
    __builtin_amdgcn_s_barrier(); \
    asm volatile("" ::: "memory"); \
    __builtin_amdgcn_s_setprio(1); \
    _Pragma("unroll") \
    for (int j = 0; j < 4; j++) \
        _Pragma("unroll") \
        for (int n = 0; n < 4; n++) \
            acc[j][n] = __builtin_amdgcn_mfma_f32_16x16x32_bf16(av[j], bv[n], acc[j][n], 0, 0, 0); \
    __builtin_amdgcn_s_setprio(0); \
}

#pragma unroll
    for (int q = 0; q < 30; q++) {
        PHASE(q % 3, q + 2, VMW(3))
    }
    PHASE(0, 32, VMW(0))   // phase 30 (slot 30%3=0), no issue (32>31)
    PHASE(1, 32, NOVM)     // phase 31 (slot 1), no issue

#undef PHASE
#undef VMW
#undef NOVM

    // epilogue: sum w_ij * relu(1 - cos); mask gc > gr (handles diagonal + doubling)
    float local = 0.f;
    int lb[4], cc[4];
#pragma unroll
    for (int n = 0; n < 4; n++) { cc[n] = wc * 64 + n * 16 + lr16; lb[n] = lcol[cc[n]]; }
    int gr0 = tr * 256 + wr * 64 + kgrp * 4;
    int gc0 = tc * 128;
#pragma unroll
    for (int m = 0; m < 4; m++) {
#pragma unroll
        for (int rg = 0; rg < 4; rg++) {
            int r = m * 16 + kgrp * 4 + rg;
            int gr = gr0 + m * 16 + rg;
            int la8 = lrow[wr * 64 + r] * 8;
#pragma unroll
            for (int n = 0; n < 4; n++) {
                float v = fmaxf(1.0f - acc[m][n][rg], 0.f);
                float wgt = (gc0 + cc[n] > gr) ? W2s[la8 + lb[n]] : 0.f;
                local += wgt * v;
            }
        }
    }
#pragma unroll
    for (int o = 32; o > 0; o >>= 1) local += __shfl_xor(local, o);
    if (lane == 0) red[w] = local;
    __syncthreads();
    if (tid == 0) {
        float s = 0.f;
#pragma unroll
        for (int k = 0; k < 8; k++) s += red[k];
        part_soft[blockIdx.x] = s;
    }
}

// ---------------- finalize: reduce all partials ----------------
__global__ __launch_bounds__(512) void finalize_kernel(
    const float* __restrict__ ws, float* __restrict__ out)
{
    __shared__ float red[8];
    int tid = threadIdx.x;
    const float invBB = 1.0f / ((float)BATCH * (float)(BATCH - 1));

    float local = 0.f;
    for (int i = tid; i < 2048; i += 512) local += ws[WS_PC + i];       // pre-scaled
    local += (ws[WS_SOFT + tid] + ws[WS_SOFT + 512 + tid]) * invBB;     // 0..1023
    if (tid < 32) local += ws[WS_SOFT + 1024 + tid] * invBB;            // 1024..1055

#pragma unroll
    for (int o = 32; o > 0; o >>= 1) local += __shfl_xor(local, o);
    if ((tid & 63) == 0) red[tid >> 6] = local;
    __syncthreads();
    if (tid == 0) {
        float s = 0.f;
#pragma unroll
        for (int k = 0; k < 8; k++) s += red[k];
        out[0] = s;
    }
}

extern "C" void kernel_launch(void* const* d_in, const int* in_sizes, int n_in,
                              void* d_out, int out_size, void* d_ws, size_t ws_size,
                              hipStream_t stream)
{
    const float* feat    = (const float*)d_in[0];
    const int*   labels  = (const int*)d_in[1];
    const float* logits  = (const float*)d_in[2];
    const float* sim     = (const float*)d_in[3];
    const float* centers = (const float*)d_in[4];
    float* out = (float*)d_out;

    float* ws = (float*)d_ws;
    unsigned short* fn = (unsigned short*)((char*)d_ws + WS_FN * 4);

    prep_kernel<<<BATCH / 4, 256, 0, stream>>>(feat, labels, logits, centers, ws + WS_PC, fn);
    soft_kernel<<<1056, 512, 0, stream>>>(fn, labels, sim, ws + WS_SOFT);
    finalize_kernel<<<1, 512, 0, stream>>>(ws, out);
}